// Round 4
// baseline (589.902 us; speedup 1.0000x reference)
//
#include <hip/hip_runtime.h>
#include <stdint.h>

// Problem constants
#define NQ    32768      // BATCH*SEQ
#define DIM   256
#define KCB   8192       // codebook size

#define T_MARGIN 0.15f   // h-only top-2 gap flag threshold (~8 sigma of err)
#define XR_CAP   16384   // compacted-query capacity (count above => keep s1)
#define LOSCALE     2048.0f
#define INV_LOSCALE (1.0f / 2048.0f)

typedef _Float16 f16;
typedef f16   v8h __attribute__((ext_vector_type(8)));
typedef f16   v4h __attribute__((ext_vector_type(4)));
typedef float v4f __attribute__((ext_vector_type(4)));

// Scratch layout (float offsets) in quantized-output region P = out + NQ
// (8.39M floats, fully overwritten by vq_gather at the end).
#define OFF_CSQ   0               // [KCB] fp32
#define OFF_CBT   8192            // [KCB*DIM] f16 hi, MFMA-frag-linear (1.05M fl)
#define OFF_CBLT  1056768         // [KCB*DIM] f16 lo*2048, frag-linear
#define OFF_CNT   2105344         // 1 int
#define OFF_LIST  2105348         // [NQ] int
#define OFF_CELL  2138120         // [NQ] u64 (8B aligned)
#define OFF_XR    2203664         // [XR_CAP*DIM] fp32 gathered flagged rows

// Frag-linear address (in halves) of element (c, d):
//   tile ct=c>>4, ks=d>>5; within tile lane=(quad= (d>>3)&3)*16 + (n=c&15),
//   half j=d&7:  off = ((ct*8+ks)*64 + quad*16 + n)*8 + j
// so a wave's B-frag load for (ct,ks) is base + lane*8 halves: contiguous 1KB.

// ---------------------------------------------------------------------------
// Prep: csq + codebook hi/lo f16 in frag-linear order + zero flag counter.
// One wave per codebook row, grid = KCB/4.
// ---------------------------------------------------------------------------
__global__ __launch_bounds__(256) void vq_prep(const float* __restrict__ cb,
                                               float* __restrict__ csq,
                                               f16* __restrict__ cbt,
                                               f16* __restrict__ cblt,
                                               int* __restrict__ cnt) {
  if (blockIdx.x == 0 && threadIdx.x == 0) *cnt = 0;
  const int w    = threadIdx.x >> 6;
  const int lane = threadIdx.x & 63;
  const int c    = blockIdx.x * 4 + w;
  // squared norm (fp32)
  float4 v = ((const float4*)(cb + (size_t)c * DIM))[lane];
  float sq = v.x * v.x + v.y * v.y + v.z * v.z + v.w * v.w;
  #pragma unroll
  for (int m = 32; m >= 1; m >>= 1) sq += __shfl_xor(sq, m, 64);
  if (lane == 0) csq[c] = sq;
  // frag-linear hi/lo: lanes 0..31 each handle one 8-dim group g
  if (lane < 32) {
    const int g = lane;
    const float* p = cb + (size_t)c * DIM + g * 8;
    float4 a = *(const float4*)p;
    float4 b = *(const float4*)(p + 4);
    v8h h, l;
    h[0]=(f16)a.x; l[0]=(f16)((a.x-(float)h[0])*LOSCALE);
    h[1]=(f16)a.y; l[1]=(f16)((a.y-(float)h[1])*LOSCALE);
    h[2]=(f16)a.z; l[2]=(f16)((a.z-(float)h[2])*LOSCALE);
    h[3]=(f16)a.w; l[3]=(f16)((a.w-(float)h[3])*LOSCALE);
    h[4]=(f16)b.x; l[4]=(f16)((b.x-(float)h[4])*LOSCALE);
    h[5]=(f16)b.y; l[5]=(f16)((b.y-(float)h[5])*LOSCALE);
    h[6]=(f16)b.z; l[6]=(f16)((b.z-(float)h[6])*LOSCALE);
    h[7]=(f16)b.w; l[7]=(f16)((b.w-(float)h[7])*LOSCALE);
    const int ct = c >> 4, n = c & 15, ks = g >> 2, quad = g & 3;
    const size_t off = ((size_t)(ct * 8 + ks) * 64 + quad * 16 + n) * 8;
    *(v8h*)&cbt[off]  = h;
    *(v8h*)&cblt[off] = l;
  }
}

// ---------------------------------------------------------------------------
// Stage 1: f16-hi distance sweep, A-in-registers, B streamed L2->VGPR.
// Block: 4 waves, 64 queries; wave wv covers c-range [wv*2048, +2048).
// Wave tile per cg: 64 q x 32 c (it=4, jt=2), K=32 MFMA steps.
// A-frag x[m=lane&15][k=quad*8+j]; D row=quad*4+r, col=lane&15.
// ---------------------------------------------------------------------------
__global__ __launch_bounds__(256, 2) void vq_stage1(
    const float* __restrict__ x, const float* __restrict__ csq,
    const f16* __restrict__ cbt, float* __restrict__ out_idx,
    int* __restrict__ cnt, int* __restrict__ list) {
  __shared__ float rd1[256];
  __shared__ float rd2[256];
  __shared__ int   ri1[256];

  const int tid  = threadIdx.x;
  const int lane = tid & 63;
  const int wv   = tid >> 6;
  const int q0   = blockIdx.x * 64;
  const int n    = lane & 15;
  const int quad = lane >> 4;

  // A-frags: 64 q x 256 d, f16 hi, in registers (4 it x 8 ks x 4 VGPR = 128).
  v8h af[4][8];
  #pragma unroll
  for (int it = 0; it < 4; ++it) {
    const float* xp = x + (size_t)(q0 + it * 16 + n) * DIM + quad * 8;
    #pragma unroll
    for (int ks = 0; ks < 8; ++ks) {
      float4 a = *(const float4*)(xp + ks * 32);
      float4 b = *(const float4*)(xp + ks * 32 + 4);
      v8h t;
      t[0]=(f16)a.x; t[1]=(f16)a.y; t[2]=(f16)a.z; t[3]=(f16)a.w;
      t[4]=(f16)b.x; t[5]=(f16)b.y; t[6]=(f16)b.z; t[7]=(f16)b.w;
      af[it][ks] = t;
    }
  }

  // Running top-2 per slot s=(it*4+r): d1,i1,d2 (no i2 needed for flagging).
  float d1[16], d2[16]; int i1[16];
  #pragma unroll
  for (int s = 0; s < 16; ++s) { d1[s] = 3.402823466e38f; d2[s] = 3.402823466e38f; i1[s] = 0; }

  const int cbase = wv * 2048;
  const int ctb   = cbase >> 4;

  v8h bc[4], bn[4];
  // frags for (cg, ksp): (ct0+jt, ks0+kk), jt,kk in {0,1}
  auto loadf = [&](int cg, int ksp, v8h* dst) {
    const int ct0 = ctb + cg * 2, ks0 = ksp * 2;
    dst[0] = *(const v8h*)&cbt[((size_t)((ct0    ) * 8 + ks0    ) * 64 + lane) * 8];
    dst[1] = *(const v8h*)&cbt[((size_t)((ct0 + 1) * 8 + ks0    ) * 64 + lane) * 8];
    dst[2] = *(const v8h*)&cbt[((size_t)((ct0    ) * 8 + ks0 + 1) * 64 + lane) * 8];
    dst[3] = *(const v8h*)&cbt[((size_t)((ct0 + 1) * 8 + ks0 + 1) * 64 + lane) * 8];
  };
  loadf(0, 0, bc);

  for (int cg = 0; cg < 64; ++cg) {
    const float cs2_0 = csq[cbase + cg * 32 + n];
    const float cs2_1 = csq[cbase + cg * 32 + 16 + n];
    v4f acc[4][2];
    #pragma unroll
    for (int it = 0; it < 4; ++it) {
      acc[it][0] = (v4f){0.f, 0.f, 0.f, 0.f};
      acc[it][1] = (v4f){0.f, 0.f, 0.f, 0.f};
    }
    #pragma unroll
    for (int ksp = 0; ksp < 4; ++ksp) {
      int ncg = cg, nksp = ksp + 1;
      if (nksp == 4) { nksp = 0; ncg = (cg + 1 < 64) ? cg + 1 : cg; }
      loadf(ncg, nksp, bn);                 // prefetch next 4 frags
      const int ks0 = ksp * 2;
      #pragma unroll
      for (int kk = 0; kk < 2; ++kk)
        #pragma unroll
        for (int jt = 0; jt < 2; ++jt) {
          v8h b = bc[kk * 2 + jt];
          #pragma unroll
          for (int it = 0; it < 4; ++it)
            acc[it][jt] = __builtin_amdgcn_mfma_f32_16x16x32_f16(
                af[it][ks0 + kk], b, acc[it][jt], 0, 0, 0);
        }
      bc[0] = bn[0]; bc[1] = bn[1]; bc[2] = bn[2]; bc[3] = bn[3];
    }
    // Fold 32 candidates into running top-2 (ascending c + strict '<').
    const int cg0 = cbase + cg * 32;
    #pragma unroll
    for (int jt = 0; jt < 2; ++jt) {
      const float cs2 = jt ? cs2_1 : cs2_0;
      const int   c   = cg0 + jt * 16 + n;
      #pragma unroll
      for (int it = 0; it < 4; ++it)
        #pragma unroll
        for (int r = 0; r < 4; ++r) {
          const float d = cs2 - 2.0f * acc[it][jt][r];
          const int s = it * 4 + r;
          if (d < d1[s]) { d2[s] = d1[s]; d1[s] = d; i1[s] = c; }
          else if (d < d2[s]) d2[s] = d;
        }
    }
  }

  // Merge over the 16 column lanes (xor 1..8 stays in the 16-group).
  #pragma unroll
  for (int s = 0; s < 16; ++s) {
    float a1 = d1[s], a2 = d2[s];
    int   ai = i1[s];
    #pragma unroll
    for (int m = 1; m <= 8; m <<= 1) {
      float o1 = __shfl_xor(a1, m, 64);
      int   oi = __shfl_xor(ai, m, 64);
      float o2 = __shfl_xor(a2, m, 64);
      bool  lt = (o1 < a1) || (o1 == a1 && oi < ai);
      float l1 = lt ? a1 : o1;
      float w1 = lt ? o1 : a1;
      int   wi = lt ? oi : ai;
      a2 = fminf(l1, fminf(a2, o2));
      a1 = w1; ai = wi;
    }
    if (n == 0) {
      const int q = (s >> 2) * 16 + quad * 4 + (s & 3);
      rd1[wv * 64 + q] = a1; rd2[wv * 64 + q] = a2; ri1[wv * 64 + q] = ai;
    }
  }
  __syncthreads();

  // Cross-wave merge (4 c-ranges) + flagging.
  if (tid < 64) {
    float a1 = rd1[tid], a2 = rd2[tid];
    int   ai = ri1[tid];
    #pragma unroll
    for (int w = 1; w < 4; ++w) {
      float o1 = rd1[w * 64 + tid], o2 = rd2[w * 64 + tid];
      int   oi = ri1[w * 64 + tid];
      bool  lt = (o1 < a1) || (o1 == a1 && oi < ai);
      float l1 = lt ? a1 : o1;
      float w1 = lt ? o1 : a1;
      int   wi = lt ? oi : ai;
      a2 = fminf(l1, fminf(a2, o2));
      a1 = w1; ai = wi;
    }
    out_idx[q0 + tid] = (float)ai;
    if (a2 - a1 <= T_MARGIN) {
      int p = atomicAdd(cnt, 1);
      if (p < XR_CAP) list[p] = q0 + tid;
    }
  }
}

// ---------------------------------------------------------------------------
// Compact: gather flagged x rows into xr, init cell keys. Wave per row.
// ---------------------------------------------------------------------------
__global__ __launch_bounds__(256) void vq_compact(
    const float* __restrict__ x, const int* __restrict__ cnt,
    const int* __restrict__ list, float* __restrict__ xr,
    unsigned long long* __restrict__ cell) {
  const int m = min(*cnt, XR_CAP);
  const int wv = threadIdx.x >> 6, lane = threadIdx.x & 63;
  for (int i = blockIdx.x * 4 + wv; i < m; i += gridDim.x * 4) {
    const int q = list[i];
    float4 v = ((const float4*)(x + (size_t)q * DIM))[lane];
    ((float4*)(xr + (size_t)i * DIM))[lane] = v;
    if (lane == 0) cell[q] = 0xFFFFFFFFFFFFFFFFULL;
  }
}

// ---------------------------------------------------------------------------
// Stage 2: exact (fp16x3) re-rank of flagged queries.
// Block = (q-tile of 16) x (c-range of 2048); 4 waves split c by 64.
// A hi+lo in registers (16 q); B hi/lo streamed frag-linear from L2.
// Result via packed-u64 lex (sortable-d, idx) atomicMin == np argmin.
// ---------------------------------------------------------------------------
__global__ __launch_bounds__(256) void vq_stage2(
    const float* __restrict__ xr, const float* __restrict__ csq,
    const f16* __restrict__ cbt, const f16* __restrict__ cblt,
    const int* __restrict__ cnt, const int* __restrict__ list,
    unsigned long long* __restrict__ cell) {
  const int count = min(*cnt, XR_CAP);
  const int qt = blockIdx.x >> 2;
  const int cr = blockIdx.x & 3;
  if (qt * 16 >= count) return;
  const int tid = threadIdx.x, lane = tid & 63, wv = tid >> 6;
  const int n = lane & 15, quad = lane >> 4;

  const int qrow = min(qt * 16 + n, count - 1);
  const float* xp = xr + (size_t)qrow * DIM + quad * 8;
  v8h ah[8], al[8];
  #pragma unroll
  for (int ks = 0; ks < 8; ++ks) {
    float4 a = *(const float4*)(xp + ks * 32);
    float4 b = *(const float4*)(xp + ks * 32 + 4);
    v8h h, l;
    h[0]=(f16)a.x; l[0]=(f16)((a.x-(float)h[0])*LOSCALE);
    h[1]=(f16)a.y; l[1]=(f16)((a.y-(float)h[1])*LOSCALE);
    h[2]=(f16)a.z; l[2]=(f16)((a.z-(float)h[2])*LOSCALE);
    h[3]=(f16)a.w; l[3]=(f16)((a.w-(float)h[3])*LOSCALE);
    h[4]=(f16)b.x; l[4]=(f16)((b.x-(float)h[4])*LOSCALE);
    h[5]=(f16)b.y; l[5]=(f16)((b.y-(float)h[5])*LOSCALE);
    h[6]=(f16)b.z; l[6]=(f16)((b.z-(float)h[6])*LOSCALE);
    h[7]=(f16)b.w; l[7]=(f16)((b.w-(float)h[7])*LOSCALE);
    ah[ks] = h; al[ks] = l;
  }

  float bd[4]; int bi[4];
  #pragma unroll
  for (int r = 0; r < 4; ++r) { bd[r] = 3.402823466e38f; bi[r] = 0; }

  const int cbase = cr * 2048;
  for (int ch = 0; ch < 8; ++ch) {
    v4f a1[4], a2[4];
    #pragma unroll
    for (int jt = 0; jt < 4; ++jt) {
      a1[jt] = (v4f){0.f, 0.f, 0.f, 0.f};
      a2[jt] = (v4f){0.f, 0.f, 0.f, 0.f};
    }
    const int ct0 = (cbase + ch * 256 + wv * 64) >> 4;
    #pragma unroll
    for (int ks = 0; ks < 8; ++ks) {
      #pragma unroll
      for (int jt = 0; jt < 4; ++jt) {
        const size_t off = ((size_t)((ct0 + jt) * 8 + ks) * 64 + lane) * 8;
        v8h bh = *(const v8h*)&cbt[off];
        v8h bl = *(const v8h*)&cblt[off];
        a1[jt] = __builtin_amdgcn_mfma_f32_16x16x32_f16(ah[ks], bh, a1[jt], 0, 0, 0);
        a2[jt] = __builtin_amdgcn_mfma_f32_16x16x32_f16(ah[ks], bl, a2[jt], 0, 0, 0);
        a2[jt] = __builtin_amdgcn_mfma_f32_16x16x32_f16(al[ks], bh, a2[jt], 0, 0, 0);
      }
    }
    #pragma unroll
    for (int jt = 0; jt < 4; ++jt) {
      const int c = cbase + ch * 256 + wv * 64 + jt * 16 + n;
      const float cs2 = csq[c];
      #pragma unroll
      for (int r = 0; r < 4; ++r) {
        const float d = cs2 - 2.0f * (a1[jt][r] + a2[jt][r] * INV_LOSCALE);
        if (d < bd[r]) { bd[r] = d; bi[r] = c; }   // c ascending => first occ.
      }
    }
  }

  __shared__ unsigned long long red[4][16];
  #pragma unroll
  for (int r = 0; r < 4; ++r) {
    unsigned ub = __float_as_uint(bd[r]);
    ub ^= (ub >> 31) ? 0xFFFFFFFFu : 0x80000000u;   // sortable float key
    unsigned long long key = ((unsigned long long)ub << 32) | (unsigned)bi[r];
    #pragma unroll
    for (int m = 1; m <= 8; m <<= 1) {
      unsigned long long o = __shfl_xor(key, m, 64);
      if (o < key) key = o;
    }
    if (n == 0) red[wv][quad * 4 + r] = key;
  }
  __syncthreads();
  if (tid < 16) {
    unsigned long long k = red[0][tid];
    #pragma unroll
    for (int w = 1; w < 4; ++w) {
      unsigned long long o = red[w][tid];
      if (o < k) k = o;
    }
    const int q = list[min(qt * 16 + tid, count - 1)];
    atomicMin(&cell[q], k);
  }
}

// ---------------------------------------------------------------------------
// Fix-up: write re-ranked indices for flagged queries.
// ---------------------------------------------------------------------------
__global__ __launch_bounds__(256) void vq_fix(const int* __restrict__ cnt,
                                              const int* __restrict__ list,
                                              const unsigned long long* __restrict__ cell,
                                              float* __restrict__ out_idx) {
  const int count = min(*cnt, XR_CAP);
  for (int i = blockIdx.x * 256 + threadIdx.x; i < count; i += gridDim.x * 256) {
    const int q = list[i];
    out_idx[q] = (float)(unsigned)(cell[q] & 0xFFFFFFFFu);
  }
}

// ---------------------------------------------------------------------------
// Gather codebook rows per final index. One wave per query.
// ---------------------------------------------------------------------------
__global__ __launch_bounds__(256) void vq_gather(const float* __restrict__ cb,
                                                 const float* __restrict__ idxf,
                                                 float* __restrict__ outq) {
  const int q    = blockIdx.x * 4 + (threadIdx.x >> 6);
  const int lane = threadIdx.x & 63;
  const int idx  = (int)idxf[q];
  float4 v = ((const float4*)(cb + (size_t)idx * DIM))[lane];
  ((float4*)(outq + (size_t)q * DIM))[lane] = v;
}

// ---------------------------------------------------------------------------
extern "C" void kernel_launch(void* const* d_in, const int* in_sizes, int n_in,
                              void* d_out, int out_size, void* d_ws, size_t ws_size,
                              hipStream_t stream) {
  const float* x  = (const float*)d_in[0];   // [NQ, DIM]
  const float* cb = (const float*)d_in[1];   // [KCB, DIM]
  float* out      = (float*)d_out;           // [NQ] idx ++ [NQ*DIM] quantized

  float* P = out + NQ;                       // scratch (gather rewrites it)
  float* csq  = P + OFF_CSQ;
  f16*   cbt  = (f16*)(P + OFF_CBT);
  f16*   cblt = (f16*)(P + OFF_CBLT);
  int*   cnt  = (int*)(P + OFF_CNT);
  int*   lst  = (int*)(P + OFF_LIST);
  unsigned long long* cel = (unsigned long long*)(P + OFF_CELL);
  float* xr   = P + OFF_XR;
  float* outq = P;

  vq_prep   <<<KCB / 4, 256, 0, stream>>>(cb, csq, cbt, cblt, cnt);
  vq_stage1 <<<NQ / 64, 256, 0, stream>>>(x, csq, cbt, out, cnt, lst);
  vq_compact<<<256,     256, 0, stream>>>(x, cnt, lst, xr, cel);
  vq_stage2 <<<(XR_CAP / 16) * 4, 256, 0, stream>>>(xr, csq, cbt, cblt, cnt, lst, cel);
  vq_fix    <<<32,      256, 0, stream>>>(cnt, lst, cel, out);
  vq_gather <<<NQ / 4,  256, 0, stream>>>(cb, out, outq);
}

// Round 5
// 323.545 us; speedup vs baseline: 1.8232x; 1.8232x over previous
//
#include <hip/hip_runtime.h>
#include <stdint.h>

// Problem constants
#define NQ    32768      // BATCH*SEQ
#define DIM   256
#define KCB   8192       // codebook size

#define T_MARGIN 0.12f   // h-only top-2 gap flag threshold (~8 sigma of err)
#define XR_CAP   16384   // compacted-query capacity
#define LOSCALE     2048.0f
#define INV_LOSCALE (1.0f / 2048.0f)

typedef _Float16 f16;
typedef f16   v8h __attribute__((ext_vector_type(8)));
typedef f16   v4h __attribute__((ext_vector_type(4)));
typedef float v4f __attribute__((ext_vector_type(4)));
typedef const __attribute__((address_space(1))) uint32_t* gas_p;
typedef __attribute__((address_space(3))) uint32_t*       las_p;

// Scratch layout (float offsets) in quantized-output region P = out + NQ
// (8,388,608 floats, fully overwritten by vq_gather at the end).
#define OFF_CSQ   0               // [KCB] fp32
#define OFF_CBT   8192            // [KCB*DIM] f16 hi, frag-linear
#define OFF_CBLT  1056768         // [KCB*DIM] f16 lo*2048, frag-linear
#define OFF_CNT   2105344         // 1 int
#define OFF_LIST  2105348         // [NQ] int
#define OFF_CELL  2138118         // [NQ] u64 (8B aligned)
#define OFF_XR    2203656         // [XR_CAP*DIM] fp32 (16B aligned)
#define OFF_PD1   6397960         // [4*NQ] fp32 partial d1
#define OFF_PD2   6529032         // [4*NQ] fp32 partial d2
#define OFF_PI1   6660104         // [4*NQ] int  partial i1
// end 6791176 < 8388608 ✓

// Frag-linear address (halves) of codebook element (c, d):
//   ct=c>>4, ks=d>>5, quad=(d>>3)&3, n=c&15, j=d&7
//   off = ((ct*8+ks)*64 + quad*16 + n)*8 + j
// A wave's B-frag for (ct,ks) = base + lane*8: one contiguous 1 KB load.

// ---------------------------------------------------------------------------
// Prep: csq + codebook hi/lo f16 frag-linear + zero flag counter.
// ---------------------------------------------------------------------------
__global__ __launch_bounds__(256) void vq_prep(const float* __restrict__ cb,
                                               float* __restrict__ csq,
                                               f16* __restrict__ cbt,
                                               f16* __restrict__ cblt,
                                               int* __restrict__ cnt) {
  if (blockIdx.x == 0 && threadIdx.x == 0) *cnt = 0;
  const int w    = threadIdx.x >> 6;
  const int lane = threadIdx.x & 63;
  const int c    = blockIdx.x * 4 + w;
  float4 v = ((const float4*)(cb + (size_t)c * DIM))[lane];
  float sq = v.x * v.x + v.y * v.y + v.z * v.z + v.w * v.w;
  #pragma unroll
  for (int m = 32; m >= 1; m >>= 1) sq += __shfl_xor(sq, m, 64);
  if (lane == 0) csq[c] = sq;
  if (lane < 32) {
    const int g = lane;
    const float* p = cb + (size_t)c * DIM + g * 8;
    float4 a = *(const float4*)p;
    float4 b = *(const float4*)(p + 4);
    v8h h, l;
    h[0]=(f16)a.x; l[0]=(f16)((a.x-(float)h[0])*LOSCALE);
    h[1]=(f16)a.y; l[1]=(f16)((a.y-(float)h[1])*LOSCALE);
    h[2]=(f16)a.z; l[2]=(f16)((a.z-(float)h[2])*LOSCALE);
    h[3]=(f16)a.w; l[3]=(f16)((a.w-(float)h[3])*LOSCALE);
    h[4]=(f16)b.x; l[4]=(f16)((b.x-(float)h[4])*LOSCALE);
    h[5]=(f16)b.y; l[5]=(f16)((b.y-(float)h[5])*LOSCALE);
    h[6]=(f16)b.z; l[6]=(f16)((b.z-(float)h[6])*LOSCALE);
    h[7]=(f16)b.w; l[7]=(f16)((b.w-(float)h[7])*LOSCALE);
    const int ct = c >> 4, n = c & 15, ks = g >> 2, quad = g & 3;
    const size_t off = ((size_t)(ct * 8 + ks) * 64 + quad * 16 + n) * 8;
    *(v8h*)&cbt[off]  = h;
    *(v8h*)&cblt[off] = l;
  }
}

// ---------------------------------------------------------------------------
// Stage 1: f16-hi distance sweep.
// Grid 1024 = 256 q-blocks x 4 c-quarters. Block: 4 waves x 32 q = 128 q,
// c-range 2048, swept in 32 chunks of 64 c. Chunk (64c x 256d = 32 KB,
// frag-linear) staged whole into an LDS ring-2 via global_load_lds; ONE
// barrier per chunk. A-frags (32 q x 256 d f16 = 64 VGPR) live in registers.
// Per-wave per-chunk: 64 MFMA, 32 ds_read_b128, branchless top-2 fold.
// Partial (d1,d2,i1) per (c-quarter, q) written to scratch; merged later.
// ---------------------------------------------------------------------------
__global__ __launch_bounds__(256, 2) void vq_stage1(
    const float* __restrict__ x, const float* __restrict__ csq,
    const f16* __restrict__ cbt, float* __restrict__ pd1,
    float* __restrict__ pd2, int* __restrict__ pi1) {
  __shared__ f16 bufs[2][64 * 256];   // 2 x 32 KB ring

  const int tid  = threadIdx.x;
  const int lane = tid & 63;
  const int wv   = tid >> 6;
  const int n    = lane & 15;
  const int quad = lane >> 4;
  const int bq   = blockIdx.x >> 2;   // q-block
  const int cq   = blockIdx.x & 3;    // c-quarter
  const int qb   = bq * 128 + wv * 32;
  const int cqb  = cq * 2048;

  // DMA one 64c chunk (32 KB, verbatim frag-linear image) into bufs[ch&1].
  auto issue = [&](int ch) {
    const f16* src = cbt + (size_t)(cq * 128 + ch * 4) * 4096;
    f16* dst = &bufs[ch & 1][0];
    #pragma unroll
    for (int i = 0; i < 8; ++i) {
      const int u = wv * 512 + i * 64;          // wave-uniform 16B-unit base
      __builtin_amdgcn_global_load_lds((gas_p)(src + (size_t)(u + lane) * 8),
                                       (las_p)(dst + (size_t)u * 8), 16, 0, 0);
    }
  };

  issue(0);   // chunk 0 in flight under the A-frag load

  // A-frags: 32 q x 256 d -> f16, in registers (2 it x 8 ks x 4 VGPR = 64).
  v8h af[2][8];
  #pragma unroll
  for (int it = 0; it < 2; ++it) {
    const float* xp = x + (size_t)(qb + it * 16 + n) * DIM + quad * 8;
    #pragma unroll
    for (int ks = 0; ks < 8; ++ks) {
      float4 a = *(const float4*)(xp + ks * 32);
      float4 b = *(const float4*)(xp + ks * 32 + 4);
      v8h t;
      t[0]=(f16)a.x; t[1]=(f16)a.y; t[2]=(f16)a.z; t[3]=(f16)a.w;
      t[4]=(f16)b.x; t[5]=(f16)b.y; t[6]=(f16)b.z; t[7]=(f16)b.w;
      af[it][ks] = t;
    }
  }

  float d1[8], d2[8]; int i1[8];      // slot s = it*4 + r
  #pragma unroll
  for (int s = 0; s < 8; ++s) {
    d1[s] = 3.402823466e38f; d2[s] = 3.402823466e38f; i1[s] = 0;
  }

  for (int ch = 0; ch < 32; ++ch) {
    __syncthreads();                  // chunk ch resident (vmcnt drained)
    if (ch + 1 < 32) issue(ch + 1);   // prefetch next into other buffer
    const f16* B = &bufs[ch & 1][0];

    v4f acc[2][4];
    #pragma unroll
    for (int it = 0; it < 2; ++it)
      #pragma unroll
      for (int jt = 0; jt < 4; ++jt) acc[it][jt] = (v4f){0.f, 0.f, 0.f, 0.f};

    #pragma unroll
    for (int ks = 0; ks < 8; ++ks) {
      #pragma unroll
      for (int jt = 0; jt < 4; ++jt) {
        v8h bf = *(const v8h*)&B[(size_t)(jt * 8 + ks) * 512 + lane * 8];
        acc[0][jt] = __builtin_amdgcn_mfma_f32_16x16x32_f16(af[0][ks], bf, acc[0][jt], 0, 0, 0);
        acc[1][jt] = __builtin_amdgcn_mfma_f32_16x16x32_f16(af[1][ks], bf, acc[1][jt], 0, 0, 0);
      }
    }

    // Branchless top-2 fold: 6 VALU/candidate. c ascending + strict '<'
    // keeps first occurrence (np tie-break).
    const int cb0 = cqb + ch * 64;
    #pragma unroll
    for (int jt = 0; jt < 4; ++jt) {
      const int   cidx = cb0 + jt * 16 + n;
      const float cs2  = csq[cidx];
      #pragma unroll
      for (int it = 0; it < 2; ++it)
        #pragma unroll
        for (int r = 0; r < 4; ++r) {
          const float d = fmaf(acc[it][jt][r], -2.0f, cs2);
          const int s = it * 4 + r;
          const bool lt = d < d1[s];
          d2[s] = fminf(d2[s], fmaxf(d1[s], d));
          i1[s] = lt ? cidx : i1[s];
          d1[s] = fminf(d1[s], d);
        }
    }
  }

  // Merge over the 16 column lanes (xor 1..8 stays inside the n-group),
  // lexicographic (d, idx); exact second-best via loser-min trick.
  #pragma unroll
  for (int s = 0; s < 8; ++s) {
    float a1 = d1[s], a2 = d2[s];
    int   ai = i1[s];
    #pragma unroll
    for (int m = 1; m <= 8; m <<= 1) {
      float o1 = __shfl_xor(a1, m, 64);
      int   oi = __shfl_xor(ai, m, 64);
      float o2 = __shfl_xor(a2, m, 64);
      bool  lt = (o1 < a1) || (o1 == a1 && oi < ai);
      float l1 = lt ? a1 : o1;
      float w1 = lt ? o1 : a1;
      int   wi = lt ? oi : ai;
      a2 = fminf(l1, fminf(a2, o2));
      a1 = w1; ai = wi;
    }
    if (n == 0) {                     // 4 lanes (quad 0..3) hold results
      const int q = qb + (s >> 2) * 16 + quad * 4 + (s & 3);
      pd1[cq * NQ + q] = a1;
      pd2[cq * NQ + q] = a2;
      pi1[cq * NQ + q] = ai;
    }
  }
}

// ---------------------------------------------------------------------------
// Merge the 4 c-quarter partials per query; write approx index; flag
// uncertain queries (gap <= T). Grid NQ/256.
// ---------------------------------------------------------------------------
__global__ __launch_bounds__(256) void vq_merge(
    const float* __restrict__ pd1, const float* __restrict__ pd2,
    const int* __restrict__ pi1, float* __restrict__ out_idx,
    int* __restrict__ cnt, int* __restrict__ list,
    unsigned long long* __restrict__ cell) {
  const int q = blockIdx.x * 256 + threadIdx.x;
  float a1 = pd1[q], a2 = pd2[q];
  int   ai = pi1[q];
  #pragma unroll
  for (int p = 1; p < 4; ++p) {
    float o1 = pd1[p * NQ + q], o2 = pd2[p * NQ + q];
    int   oi = pi1[p * NQ + q];
    bool  lt = (o1 < a1) || (o1 == a1 && oi < ai);
    float l1 = lt ? a1 : o1;
    float w1 = lt ? o1 : a1;
    int   wi = lt ? oi : ai;
    a2 = fminf(l1, fminf(a2, o2));
    a1 = w1; ai = wi;
  }
  out_idx[q] = (float)ai;
  if (a2 - a1 <= T_MARGIN) {
    int pos = atomicAdd(cnt, 1);
    if (pos < XR_CAP) list[pos] = q;
    cell[q] = 0xFFFFFFFFFFFFFFFFULL;
  }
}

// ---------------------------------------------------------------------------
// Compact: gather flagged x rows into xr. Wave per row.
// ---------------------------------------------------------------------------
__global__ __launch_bounds__(256) void vq_compact(
    const float* __restrict__ x, const int* __restrict__ cnt,
    const int* __restrict__ list, float* __restrict__ xr) {
  const int m = min(*cnt, XR_CAP);
  const int wv = threadIdx.x >> 6, lane = threadIdx.x & 63;
  for (int i = blockIdx.x * 4 + wv; i < m; i += gridDim.x * 4) {
    const int q = list[i];
    float4 v = ((const float4*)(x + (size_t)q * DIM))[lane];
    ((float4*)(xr + (size_t)i * DIM))[lane] = v;
  }
}

// ---------------------------------------------------------------------------
// Stage 2: exact (fp16x3) re-rank of flagged queries.
// Block = (q-tile of 16) x (c-range of 2048); 4 waves split c by 64.
// Packed-u64 lex (sortable-d, idx) atomicMin == np first-occurrence argmin.
// ---------------------------------------------------------------------------
__global__ __launch_bounds__(256) void vq_stage2(
    const float* __restrict__ xr, const float* __restrict__ csq,
    const f16* __restrict__ cbt, const f16* __restrict__ cblt,
    const int* __restrict__ cnt, const int* __restrict__ list,
    unsigned long long* __restrict__ cell) {
  const int count = min(*cnt, XR_CAP);
  const int qt = blockIdx.x >> 2;
  const int cr = blockIdx.x & 3;
  if (qt * 16 >= count) return;
  const int tid = threadIdx.x, lane = tid & 63, wv = tid >> 6;
  const int n = lane & 15, quad = lane >> 4;

  const int qrow = min(qt * 16 + n, count - 1);
  const float* xp = xr + (size_t)qrow * DIM + quad * 8;
  v8h ah[8], al[8];
  #pragma unroll
  for (int ks = 0; ks < 8; ++ks) {
    float4 a = *(const float4*)(xp + ks * 32);
    float4 b = *(const float4*)(xp + ks * 32 + 4);
    v8h h, l;
    h[0]=(f16)a.x; l[0]=(f16)((a.x-(float)h[0])*LOSCALE);
    h[1]=(f16)a.y; l[1]=(f16)((a.y-(float)h[1])*LOSCALE);
    h[2]=(f16)a.z; l[2]=(f16)((a.z-(float)h[2])*LOSCALE);
    h[3]=(f16)a.w; l[3]=(f16)((a.w-(float)h[3])*LOSCALE);
    h[4]=(f16)b.x; l[4]=(f16)((b.x-(float)h[4])*LOSCALE);
    h[5]=(f16)b.y; l[5]=(f16)((b.y-(float)h[5])*LOSCALE);
    h[6]=(f16)b.z; l[6]=(f16)((b.z-(float)h[6])*LOSCALE);
    h[7]=(f16)b.w; l[7]=(f16)((b.w-(float)h[7])*LOSCALE);
    ah[ks] = h; al[ks] = l;
  }

  float bd[4]; int bi[4];
  #pragma unroll
  for (int r = 0; r < 4; ++r) { bd[r] = 3.402823466e38f; bi[r] = 0; }

  const int cbase = cr * 2048;
  for (int ch = 0; ch < 8; ++ch) {
    v4f a1[4], a2[4];
    #pragma unroll
    for (int jt = 0; jt < 4; ++jt) {
      a1[jt] = (v4f){0.f, 0.f, 0.f, 0.f};
      a2[jt] = (v4f){0.f, 0.f, 0.f, 0.f};
    }
    const int ct0 = (cbase + ch * 256 + wv * 64) >> 4;
    #pragma unroll
    for (int ks = 0; ks < 8; ++ks) {
      #pragma unroll
      for (int jt = 0; jt < 4; ++jt) {
        const size_t off = ((size_t)((ct0 + jt) * 8 + ks) * 64 + lane) * 8;
        v8h bh = *(const v8h*)&cbt[off];
        v8h bl = *(const v8h*)&cblt[off];
        a1[jt] = __builtin_amdgcn_mfma_f32_16x16x32_f16(ah[ks], bh, a1[jt], 0, 0, 0);
        a2[jt] = __builtin_amdgcn_mfma_f32_16x16x32_f16(ah[ks], bl, a2[jt], 0, 0, 0);
        a2[jt] = __builtin_amdgcn_mfma_f32_16x16x32_f16(al[ks], bh, a2[jt], 0, 0, 0);
      }
    }
    #pragma unroll
    for (int jt = 0; jt < 4; ++jt) {
      const int c = cbase + ch * 256 + wv * 64 + jt * 16 + n;
      const float cs2 = csq[c];
      #pragma unroll
      for (int r = 0; r < 4; ++r) {
        const float d = cs2 - 2.0f * (a1[jt][r] + a2[jt][r] * INV_LOSCALE);
        if (d < bd[r]) { bd[r] = d; bi[r] = c; }   // c ascending => first occ.
      }
    }
  }

  __shared__ unsigned long long red[4][16];
  #pragma unroll
  for (int r = 0; r < 4; ++r) {
    unsigned ub = __float_as_uint(bd[r]);
    ub ^= (ub >> 31) ? 0xFFFFFFFFu : 0x80000000u;   // sortable float key
    unsigned long long key = ((unsigned long long)ub << 32) | (unsigned)bi[r];
    #pragma unroll
    for (int m = 1; m <= 8; m <<= 1) {
      unsigned long long o = __shfl_xor(key, m, 64);
      if (o < key) key = o;
    }
    if (n == 0) red[wv][quad * 4 + r] = key;
  }
  __syncthreads();
  if (tid < 16) {
    unsigned long long k = red[0][tid];
    #pragma unroll
    for (int w = 1; w < 4; ++w) {
      unsigned long long o = red[w][tid];
      if (o < k) k = o;
    }
    const int q = list[min(qt * 16 + tid, count - 1)];
    atomicMin(&cell[q], k);
  }
}

// ---------------------------------------------------------------------------
// Fix-up: write re-ranked indices for flagged queries.
// ---------------------------------------------------------------------------
__global__ __launch_bounds__(256) void vq_fix(const int* __restrict__ cnt,
                                              const int* __restrict__ list,
                                              const unsigned long long* __restrict__ cell,
                                              float* __restrict__ out_idx) {
  const int count = min(*cnt, XR_CAP);
  for (int i = blockIdx.x * 256 + threadIdx.x; i < count; i += gridDim.x * 256) {
    const int q = list[i];
    out_idx[q] = (float)(unsigned)(cell[q] & 0xFFFFFFFFu);
  }
}

// ---------------------------------------------------------------------------
// Gather codebook rows per final index. One wave per query.
// ---------------------------------------------------------------------------
__global__ __launch_bounds__(256) void vq_gather(const float* __restrict__ cb,
                                                 const float* __restrict__ idxf,
                                                 float* __restrict__ outq) {
  const int q    = blockIdx.x * 4 + (threadIdx.x >> 6);
  const int lane = threadIdx.x & 63;
  const int idx  = (int)idxf[q];
  float4 v = ((const float4*)(cb + (size_t)idx * DIM))[lane];
  ((float4*)(outq + (size_t)q * DIM))[lane] = v;
}

// ---------------------------------------------------------------------------
extern "C" void kernel_launch(void* const* d_in, const int* in_sizes, int n_in,
                              void* d_out, int out_size, void* d_ws, size_t ws_size,
                              hipStream_t stream) {
  const float* x  = (const float*)d_in[0];   // [NQ, DIM]
  const float* cb = (const float*)d_in[1];   // [KCB, DIM]
  float* out      = (float*)d_out;           // [NQ] idx ++ [NQ*DIM] quantized

  float* P = out + NQ;                       // scratch (gather rewrites it)
  float* csq  = P + OFF_CSQ;
  f16*   cbt  = (f16*)(P + OFF_CBT);
  f16*   cblt = (f16*)(P + OFF_CBLT);
  int*   cnt  = (int*)(P + OFF_CNT);
  int*   lst  = (int*)(P + OFF_LIST);
  unsigned long long* cel = (unsigned long long*)(P + OFF_CELL);
  float* xr   = P + OFF_XR;
  float* pd1  = P + OFF_PD1;
  float* pd2  = P + OFF_PD2;
  int*   pi1  = (int*)(P + OFF_PI1);
  float* outq = P;

  vq_prep   <<<KCB / 4,  256, 0, stream>>>(cb, csq, cbt, cblt, cnt);
  vq_stage1 <<<1024,     256, 0, stream>>>(x, csq, cbt, pd1, pd2, pi1);
  vq_merge  <<<NQ / 256, 256, 0, stream>>>(pd1, pd2, pi1, out, cnt, lst, cel);
  vq_compact<<<256,      256, 0, stream>>>(x, cnt, lst, xr);
  vq_stage2 <<<(XR_CAP / 16) * 4, 256, 0, stream>>>(xr, csq, cbt, cblt, cnt, lst, cel);
  vq_fix    <<<32,       256, 0, stream>>>(cnt, lst, cel, out);
  vq_gather <<<NQ / 4,   256, 0, stream>>>(cb, out, outq);
}